// Round 3
// baseline (149.253 us; speedup 1.0000x reference)
//
#include <hip/hip_runtime.h>

#define T_LEN 16384
#define CIN   64
#define COUT  64
#define KTAPS 127
#define TN    512          // t-tile per block
#define XROWS 640          // staged x rows (w = 0..638 used)
#define WT_KS 4096         // COUT*CIN halfwords per tap slice

typedef __attribute__((ext_vector_type(8)))  __bf16 bf16x8;
typedef __attribute__((ext_vector_type(16))) float  f32x16;
typedef __attribute__((ext_vector_type(4)))  float  float4v;

__device__ inline unsigned short f2bf(float f) {
    unsigned u = __builtin_bit_cast(unsigned, f);
    u += 0x7fffu + ((u >> 16) & 1u);        // round-to-nearest-even
    return (unsigned short)(u >> 16);
}

// 16-slot swizzle: row r, logical halfword c (0..63) stored at
//   r*64 + ((c>>2) ^ (r&15))*4 + (c&3)
// Wt[kp][o][i] = bf16(W[o][i][126-kp]) with this swizzle baked in, so
// global_load_lds stages it linearly (m173 pattern).
__global__ void wt_transform(const float* __restrict__ W,
                             unsigned short* __restrict__ Wt) {
    int tid = blockIdx.x * 256 + threadIdx.x;   // o*64 + i, 4096 threads
    int o = tid >> 6, i = tid & 63;
    int hw = o * 64 + (((i >> 2) ^ (o & 15)) << 2) + (i & 3);
    const float* src = W + tid * KTAPS;         // W[o][i][*], contiguous
    unsigned short* dst = Wt + hw;
    for (int kp = 0; kp < KTAPS; ++kp)
        dst[kp * WT_KS] = f2bf(src[126 - kp]);
}

#define GLL16(g, l)                                                        \
    __builtin_amdgcn_global_load_lds(                                      \
        (const __attribute__((address_space(1))) void*)(g),                \
        (__attribute__((address_space(3))) void*)(l), 16, 0, 0)

__global__ __launch_bounds__(256, 1)
void conv_mfma(const float* __restrict__ x,
               const unsigned short* __restrict__ Wt,
               float* __restrict__ y) {
    __shared__ unsigned short as_[2][WT_KS];    // 16 KB, LDS offset 0
    __shared__ unsigned short xs[XROWS * 64];   // 80 KB

    const int tid = threadIdx.x;
    const int bb  = blockIdx.x >> 5;      // batch
    const int tt  = blockIdx.x & 31;      // t-tile
    const int t0  = tt * TN;

    // ---- stage x window [t0-64, t0+575] transposed into LDS, 16-slot swizzle
    {
        const int cin = tid >> 2;             // 0..63
        const int s   = tid & 3;              // 16B chunk within 16-row group
        const float* xrow = x + (bb * CIN + cin) * T_LEN;
        const int p = cin >> 2, c3 = cin & 3;
        for (int j = 0; j < 40; ++j) {
            const int w = 16 * j + 4 * s;
            const int u = t0 - 64 + w;        // global t (16B aligned)
            float4v v;
            if (u >= 0 && u + 4 <= T_LEN) {
                v = *(const float4v*)(xrow + u);
            } else {
                v.x = (u + 0 >= 0 && u + 0 < T_LEN) ? xrow[u + 0] : 0.f;
                v.y = (u + 1 >= 0 && u + 1 < T_LEN) ? xrow[u + 1] : 0.f;
                v.z = (u + 2 >= 0 && u + 2 < T_LEN) ? xrow[u + 2] : 0.f;
                v.w = (u + 3 >= 0 && u + 3 < T_LEN) ? xrow[u + 3] : 0.f;
            }
            #pragma unroll
            for (int e = 0; e < 4; ++e) {
                const int we = w + e;
                const float fv = (e == 0) ? v.x : (e == 1) ? v.y : (e == 2) ? v.z : v.w;
                xs[we * 64 + ((p ^ (we & 15)) << 2) + c3] = f2bf(fv);
            }
        }
    }

    // ---- per-block A staging: 8 KB/tap via global_load_lds width-16
    auto stageA = [&](int kp, int buf) {
        const char* g = (const char*)(Wt + kp * WT_KS) + tid * 16;
        char* l = (char*)(&as_[buf][0]) + tid * 16;
        GLL16(g, l);
        GLL16(g + 4096, l + 4096);
    };

    stageA(0, 0);
    asm volatile("s_waitcnt vmcnt(0)" ::: "memory");
    __syncthreads();   // xs + as_[0] ready

    const int lane   = tid & 63;
    const int wv     = tid >> 6;          // wave 0..3
    const int l31    = lane & 31;
    const int kg     = lane >> 5;         // K-half (0/1)
    const int twbase = wv * 128;          // wave's 128-t range
    const int brow0  = twbase + l31 + 1;  // xs row at k'=0

    // per-lane A byte offsets within an as_ buffer (loop-invariant)
    int aoff[2][4][2];
    #pragma unroll
    for (int m = 0; m < 2; ++m)
        #pragma unroll
        for (int cc = 0; cc < 4; ++cc)
            #pragma unroll
            for (int h = 0; h < 2; ++h)
                aoff[m][cc][h] = (l31 + 32 * m) * 128 +
                                 (((4 * cc + 2 * kg + h) ^ (l31 & 15)) << 3);

    const char* asbase = (const char*)&as_[0][0];
    const char* xsbase = (const char*)&xs[0];

    f32x16 acc[2][4] = {};                // [m: o-tile][n: t-tile]

    auto tap = [&](int kp, int buf) {
        if (kp + 1 < KTAPS) stageA(kp + 1, buf ^ 1);   // issue early
        const int rb   = brow0 + kp;
        const int rb15 = rb & 15;
        const char* arow = asbase + buf * 8192;
        const char* xrowp = xsbase + rb * 128;
        #pragma unroll
        for (int cc = 0; cc < 4; ++cc) {
            bf16x8 a[2];
            #pragma unroll
            for (int m = 0; m < 2; ++m) {
                uint2 lo = *(const uint2*)(arow + aoff[m][cc][0]);
                uint2 hi = *(const uint2*)(arow + aoff[m][cc][1]);
                uint4 t4 = {lo.x, lo.y, hi.x, hi.y};
                a[m] = __builtin_bit_cast(bf16x8, t4);
            }
            const int o0 = (((4 * cc + 2 * kg + 0) ^ rb15) << 3);
            const int o1 = (((4 * cc + 2 * kg + 1) ^ rb15) << 3);
            #pragma unroll
            for (int n = 0; n < 4; ++n) {
                uint2 lo = *(const uint2*)(xrowp + n * 4096 + o0);
                uint2 hi = *(const uint2*)(xrowp + n * 4096 + o1);
                uint4 t4 = {lo.x, lo.y, hi.x, hi.y};
                bf16x8 b = __builtin_bit_cast(bf16x8, t4);
                acc[0][n] = __builtin_amdgcn_mfma_f32_32x32x16_bf16(a[0], b, acc[0][n], 0, 0, 0);
                acc[1][n] = __builtin_amdgcn_mfma_f32_32x32x16_bf16(a[1], b, acc[1][n], 0, 0, 0);
            }
        }
        // drain staging loads (issued a full tap ago: no stall expected)
        asm volatile("s_waitcnt vmcnt(0)" ::: "memory");
        __builtin_amdgcn_s_barrier();
    };

    for (int kp = 0; kp < KTAPS - 1; kp += 2) {   // 0..125
        tap(kp + 0, 0);
        tap(kp + 1, 1);
    }
    tap(KTAPS - 1, 0);                            // kp = 126

    // ---- epilogue: D col = lane&31 -> t, row = (r&3)+8*(r>>2)+4*kg -> o
    const int ybase = (bb * COUT) * T_LEN;
    #pragma unroll
    for (int m = 0; m < 2; ++m) {
        #pragma unroll
        for (int n = 0; n < 4; ++n) {
            const int t = t0 + twbase + n * 32 + l31;
            #pragma unroll
            for (int r = 0; r < 16; ++r) {
                const int o = m * 32 + (r & 3) + 8 * (r >> 2) + 4 * kg;
                y[ybase + o * T_LEN + t] = acc[m][n][r];
            }
        }
    }
}

extern "C" void kernel_launch(void* const* d_in, const int* in_sizes, int n_in,
                              void* d_out, int out_size, void* d_ws, size_t ws_size,
                              hipStream_t stream) {
    const float* x = (const float*)d_in[0];
    const float* W = (const float*)d_in[1];
    float* yout = (float*)d_out;
    unsigned short* Wt = (unsigned short*)d_ws;   // 127*4096*2 B ~= 1 MB

    wt_transform<<<16, 256, 0, stream>>>(W, Wt);

    const int grid = 8 * (T_LEN / TN);            // 256 blocks
    conv_mfma<<<grid, 256, 0, stream>>>(x, Wt, yout);
}

// Round 4
// 130.858 us; speedup vs baseline: 1.1406x; 1.1406x over previous
//
#include <hip/hip_runtime.h>

#define T_LEN 16384
#define CIN   64
#define COUT  64
#define KTAPS 127
#define TN    512          // t-tile per block
#define XROWS 640          // staged x rows (w = 0..638 used)
#define WT_KS 4096         // COUT*CIN halfwords per tap slice

typedef __attribute__((ext_vector_type(8)))  __bf16 bf16x8;
typedef __attribute__((ext_vector_type(16))) float  f32x16;
typedef __attribute__((ext_vector_type(4)))  float  float4v;

__device__ inline unsigned short f2bf(float f) {
    unsigned u = __builtin_bit_cast(unsigned, f);
    u += 0x7fffu + ((u >> 16) & 1u);        // round-to-nearest-even
    return (unsigned short)(u >> 16);
}

// Wt[kp] slice (8KB) stored in MFMA-fragment order so each lane's A-fragment
// is one contiguous 16B chunk (conflict-free ds_read_b128, linear staging):
//   element (o,i) -> ((cc*2+m)*64 + kg*32 + l31)*8 + e
//   cc=i>>4, kg=(i>>3)&1, e=i&7, m=o>>5, l31=o&31;  value = bf16(W[o][i][126-kp])
__global__ void wt_transform(const float* __restrict__ W,
                             unsigned short* __restrict__ Wt) {
    int tid = blockIdx.x * 256 + threadIdx.x;   // o*64 + i, 4096 threads
    int o = tid >> 6, i = tid & 63;
    int cc = i >> 4, kg = (i >> 3) & 1, e = i & 7, m = o >> 5, l31 = o & 31;
    int hw = ((cc * 2 + m) * 64 + kg * 32 + l31) * 8 + e;
    const float* src = W + tid * KTAPS;         // W[o][i][*], contiguous
    unsigned short* dst = Wt + hw;
    for (int kp = 0; kp < KTAPS; ++kp)
        dst[kp * WT_KS] = f2bf(src[126 - kp]);
}

#define GLL16(g, l)                                                        \
    __builtin_amdgcn_global_load_lds(                                      \
        (const __attribute__((address_space(1))) void*)(g),                \
        (__attribute__((address_space(3))) void*)(l), 16, 0, 0)

__global__ __launch_bounds__(512, 2)
void conv_mfma(const float* __restrict__ x,
               const unsigned short* __restrict__ Wt,
               float* __restrict__ y) {
    // pool: xs [0,80K) | as_ [80K,112K)  (merge scratch reuses [0,64K) at end)
    __shared__ __align__(16) char pool[114688];
    unsigned short* xs = (unsigned short*)pool;         // [XROWS][64] swizzled
    char* asbase = pool + 81920;                        // 2 bufs x 2 quads x 8KB

    const int tid = threadIdx.x;
    const int bb  = blockIdx.x >> 5;      // batch
    const int tt  = blockIdx.x & 31;      // t-tile
    const int t0  = tt * TN;

    // ---- stage x window [t0-64, t0+575] transposed, 16-slot 8B swizzle:
    //      row w, cin c stored at w*64 + ((c>>2 ^ (w&15))<<2) + (c&3)
    {
        const int cin = tid >> 3;             // 0..63
        const int s   = tid & 7;
        const float* xrow = x + (bb * CIN + cin) * T_LEN;
        const int p = cin >> 2, c3 = cin & 3;
        for (int j = 0; j < 20; ++j) {
            const int w = 32 * j + 4 * s;
            const int u = t0 - 64 + w;        // global t (16B aligned)
            float4v v;
            if (u >= 0 && u + 4 <= T_LEN) {
                v = *(const float4v*)(xrow + u);
            } else {
                v.x = (u + 0 >= 0 && u + 0 < T_LEN) ? xrow[u + 0] : 0.f;
                v.y = (u + 1 >= 0 && u + 1 < T_LEN) ? xrow[u + 1] : 0.f;
                v.z = (u + 2 >= 0 && u + 2 < T_LEN) ? xrow[u + 2] : 0.f;
                v.w = (u + 3 >= 0 && u + 3 < T_LEN) ? xrow[u + 3] : 0.f;
            }
            #pragma unroll
            for (int e = 0; e < 4; ++e) {
                const int we = w + e;
                const float fv = (e == 0) ? v.x : (e == 1) ? v.y : (e == 2) ? v.z : v.w;
                xs[we * 64 + ((p ^ (we & 15)) << 2) + c3] = f2bf(fv);
            }
        }
    }

    // ---- A staging: 2 tap slices (8KB each) per phase, 512 thr x 2 GLL16
    auto stageA = [&](int k0, int k1, int buf) {
        #pragma unroll
        for (int h = 0; h < 2; ++h) {
            const int c   = tid + h * 512;        // chunk 0..1023
            const int q   = c >> 9;               // quad slice
            const int off = (c & 511) * 16;
            const char* g = (const char*)(Wt + (q ? k1 : k0) * WT_KS) + off;
            char* l = asbase + buf * 16384 + q * 8192 + off;
            GLL16(g, l);
        }
    };

    stageA(0, 64, 0);
    asm volatile("s_waitcnt vmcnt(0)" ::: "memory");
    __syncthreads();   // xs + as_[0] ready

    const int lane   = tid & 63;
    const int wv     = tid >> 6;          // 0..7
    const int quad   = wv >> 2;           // tap-half owner
    const int ww     = wv & 3;            // wave-in-quad: t-range
    const int l31    = lane & 31;
    const int kg     = lane >> 5;
    const int twbase = ww * 128;          // wave's 128-t range
    const int brow0  = twbase + l31 + 1;  // xs row at k'=0

    f32x16 acc[2][4] = {};                // [m: o-tile][n: t-tile]

    auto phase = [&](int p, int buf) {
        if (p + 1 < 64) {
            int k1 = 64 + p + 1; if (k1 > 126) k1 = 126;
            stageA(p + 1, k1, buf ^ 1);           // issue early
        }
        const int kp = quad ? 64 + p : p;
        if (quad == 0 || p < 63) {
            const char* aslice = asbase + buf * 16384 + quad * 8192;
            const int rb   = brow0 + kp;
            const int rb15 = rb & 15;
            const char* xrowp = (const char*)xs + rb * 128;
            #pragma unroll
            for (int cc = 0; cc < 4; ++cc) {
                bf16x8 a0 = *(const bf16x8*)(aslice + ((cc * 2 + 0) * 64 + lane) * 16);
                bf16x8 a1 = *(const bf16x8*)(aslice + ((cc * 2 + 1) * 64 + lane) * 16);
                const int o0 = (((4 * cc + 2 * kg + 0) ^ rb15) << 3);
                const int o1 = (((4 * cc + 2 * kg + 1) ^ rb15) << 3);
                #pragma unroll
                for (int n = 0; n < 4; ++n) {
                    uint2 lo = *(const uint2*)(xrowp + n * 4096 + o0);
                    uint2 hi = *(const uint2*)(xrowp + n * 4096 + o1);
                    uint4 t4 = {lo.x, lo.y, hi.x, hi.y};
                    bf16x8 b = __builtin_bit_cast(bf16x8, t4);
                    acc[0][n] = __builtin_amdgcn_mfma_f32_32x32x16_bf16(a0, b, acc[0][n], 0, 0, 0);
                    acc[1][n] = __builtin_amdgcn_mfma_f32_32x32x16_bf16(a1, b, acc[1][n], 0, 0, 0);
                }
            }
        }
        asm volatile("s_waitcnt vmcnt(0)" ::: "memory");
        __builtin_amdgcn_s_barrier();
    };

    for (int p = 0; p < 64; p += 2) {
        phase(p + 0, 0);
        phase(p + 1, 1);
    }

    // ---- merge quad1 partials into quad0 via LDS (xs/as_ dead now)
    __syncthreads();
    float* msm = (float*)pool;            // 64KB: plane (n*16+r) x 256 f32
    #pragma unroll
    for (int m = 0; m < 2; ++m) {
        if (quad == 1) {
            #pragma unroll
            for (int n = 0; n < 4; ++n)
                #pragma unroll
                for (int r = 0; r < 16; ++r)
                    msm[(n * 16 + r) * 256 + ww * 64 + lane] = acc[m][n][r];
        }
        __syncthreads();
        if (quad == 0) {
            #pragma unroll
            for (int n = 0; n < 4; ++n)
                #pragma unroll
                for (int r = 0; r < 16; ++r)
                    acc[m][n][r] += msm[(n * 16 + r) * 256 + ww * 64 + lane];
        }
        __syncthreads();
    }

    // ---- epilogue (quad0): D col = l31 -> t, row = (r&3)+8*(r>>2)+4*kg -> o
    if (quad == 0) {
        const int ybase = (bb * COUT) * T_LEN;
        #pragma unroll
        for (int m = 0; m < 2; ++m) {
            #pragma unroll
            for (int n = 0; n < 4; ++n) {
                const int t = t0 + twbase + n * 32 + l31;
                #pragma unroll
                for (int r = 0; r < 16; ++r) {
                    const int o = m * 32 + (r & 3) + 8 * (r >> 2) + 4 * kg;
                    y[ybase + o * T_LEN + t] = acc[m][n][r];
                }
            }
        }
    }
}

extern "C" void kernel_launch(void* const* d_in, const int* in_sizes, int n_in,
                              void* d_out, int out_size, void* d_ws, size_t ws_size,
                              hipStream_t stream) {
    const float* x = (const float*)d_in[0];
    const float* W = (const float*)d_in[1];
    float* yout = (float*)d_out;
    unsigned short* Wt = (unsigned short*)d_ws;   // 127*4096*2 B ~= 1 MB

    wt_transform<<<16, 256, 0, stream>>>(W, Wt);

    const int grid = 8 * (T_LEN / TN);            // 256 blocks
    conv_mfma<<<grid, 512, 0, stream>>>(x, Wt, yout);
}

// Round 5
// 125.888 us; speedup vs baseline: 1.1856x; 1.0395x over previous
//
#include <hip/hip_runtime.h>

#define T_LEN 16384
#define CIN   64
#define COUT  64
#define KTAPS 127
#define TN    512          // t-tile per block
#define XROWS 640          // staged x rows (w = 0..638 used)
#define WT_KS 4096         // COUT*CIN halfwords per tap slice

typedef __attribute__((ext_vector_type(8)))  __bf16 bf16x8;
typedef __attribute__((ext_vector_type(16))) float  f32x16;
typedef __attribute__((ext_vector_type(4)))  float  float4v;

__device__ inline unsigned short f2bf(float f) {
    unsigned u = __builtin_bit_cast(unsigned, f);
    u += 0x7fffu + ((u >> 16) & 1u);        // round-to-nearest-even
    return (unsigned short)(u >> 16);
}

// Wt[kp] slice (8KB) in MFMA-fragment order: each lane's A-fragment is one
// contiguous 16B chunk -> direct global_load_dwordx4 into VGPRs, L2/L1-hot.
//   element (o,i) -> ((cc*2+m)*64 + kg*32 + l31)*8 + e
//   cc=i>>4, kg=(i>>3)&1, e=i&7, m=o>>5, l31=o&31;  value = bf16(W[o][i][126-kp])
__global__ void wt_transform(const float* __restrict__ W,
                             unsigned short* __restrict__ Wt) {
    int tid = blockIdx.x * 256 + threadIdx.x;   // o*64 + i, 4096 threads
    int o = tid >> 6, i = tid & 63;
    int cc = i >> 4, kg = (i >> 3) & 1, e = i & 7, m = o >> 5, l31 = o & 31;
    int hw = ((cc * 2 + m) * 64 + kg * 32 + l31) * 8 + e;
    const float* src = W + tid * KTAPS;         // W[o][i][*], contiguous
    unsigned short* dst = Wt + hw;
    for (int kp = 0; kp < KTAPS; ++kp)
        dst[kp * WT_KS] = f2bf(src[126 - kp]);
}

__global__ __launch_bounds__(512, 2)
void conv_mfma(const float* __restrict__ x,
               const unsigned short* __restrict__ Wt,
               float* __restrict__ y) {
    // pool: xs [0,80K)  (merge scratch reuses [0,64K) at the end)
    __shared__ __align__(16) char pool[81920];
    unsigned short* xs = (unsigned short*)pool;   // [XROWS][64] swizzled

    const int tid = threadIdx.x;
    const int bb  = blockIdx.x >> 5;      // batch
    const int tt  = blockIdx.x & 31;      // t-tile
    const int t0  = tt * TN;

    // ---- stage x window [t0-64, t0+575] transposed, 16-slot 8B swizzle:
    //      row w, cin c stored at w*64 + ((c>>2 ^ (w&15))<<2) + (c&3)
    {
        const int cin = tid >> 3;             // 0..63
        const int s   = tid & 7;
        const float* xrow = x + (bb * CIN + cin) * T_LEN;
        const int p = cin >> 2, c3 = cin & 3;
        for (int j = 0; j < 20; ++j) {
            const int w = 32 * j + 4 * s;
            const int u = t0 - 64 + w;        // global t (16B aligned)
            float4v v;
            if (u >= 0 && u + 4 <= T_LEN) {
                v = *(const float4v*)(xrow + u);
            } else {
                v.x = (u + 0 >= 0 && u + 0 < T_LEN) ? xrow[u + 0] : 0.f;
                v.y = (u + 1 >= 0 && u + 1 < T_LEN) ? xrow[u + 1] : 0.f;
                v.z = (u + 2 >= 0 && u + 2 < T_LEN) ? xrow[u + 2] : 0.f;
                v.w = (u + 3 >= 0 && u + 3 < T_LEN) ? xrow[u + 3] : 0.f;
            }
            #pragma unroll
            for (int e = 0; e < 4; ++e) {
                const int we = w + e;
                const float fv = (e == 0) ? v.x : (e == 1) ? v.y : (e == 2) ? v.z : v.w;
                xs[we * 64 + ((p ^ (we & 15)) << 2) + c3] = f2bf(fv);
            }
        }
    }

    const int lane   = tid & 63;
    const int wv     = tid >> 6;          // 0..7
    const int quad   = wv >> 2;           // tap-half owner
    const int ww     = wv & 3;            // wave-in-quad: t-range
    const int l31    = lane & 31;
    const int kg     = lane >> 5;
    const int twbase = ww * 128;          // wave's 128-t range
    const int brow0  = twbase + l31 + 1;  // xs row at k'=0

    const int kp0  = quad ? 64 : 0;
    const int ntap = quad ? 63 : 64;

    // per-lane A-fragment global base: + kp*8192 + f*1024, f = cc*2+m
    const char* ab = (const char*)Wt + lane * 16;

    f32x16 acc[2][4] = {};                // [m: o-tile][n: t-tile]
    uint4 a0r[8], a1r[8];                 // ping-pong A prefetch

    #define LOADA(dst, kp)                                                  \
        {   const char* p_ = ab + (kp) * 8192;                              \
            _Pragma("unroll")                                               \
            for (int f = 0; f < 8; ++f)                                     \
                dst[f] = *(const uint4*)(p_ + f * 1024); }

    LOADA(a0r, kp0);                       // overlaps with the barrier
    __syncthreads();                       // xs ready (only barrier pre-merge)

    #define COMPUTE(ar, kp)                                                 \
        {   const int rb_   = brow0 + (kp);                                 \
            const int rb15_ = rb_ & 15;                                     \
            const char* xrowp_ = (const char*)xs + rb_ * 128;               \
            _Pragma("unroll")                                               \
            for (int cc = 0; cc < 4; ++cc) {                                \
                bf16x8 a0 = __builtin_bit_cast(bf16x8, ar[cc * 2 + 0]);     \
                bf16x8 a1 = __builtin_bit_cast(bf16x8, ar[cc * 2 + 1]);     \
                const int o0 = (((4 * cc + 2 * kg + 0) ^ rb15_) << 3);      \
                const int o1 = (((4 * cc + 2 * kg + 1) ^ rb15_) << 3);      \
                _Pragma("unroll")                                           \
                for (int n = 0; n < 4; ++n) {                               \
                    uint2 lo = *(const uint2*)(xrowp_ + n * 4096 + o0);     \
                    uint2 hi = *(const uint2*)(xrowp_ + n * 4096 + o1);     \
                    uint4 t4 = {lo.x, lo.y, hi.x, hi.y};                    \
                    bf16x8 b = __builtin_bit_cast(bf16x8, t4);              \
                    acc[0][n] = __builtin_amdgcn_mfma_f32_32x32x16_bf16(a0, b, acc[0][n], 0, 0, 0); \
                    acc[1][n] = __builtin_amdgcn_mfma_f32_32x32x16_bf16(a1, b, acc[1][n], 0, 0, 0); \
                } } }

    // barrier-free main loop: waves drift freely over their tap ranges
    for (int i = 0; i < ntap; i += 2) {
        if (i + 1 < ntap) LOADA(a1r, kp0 + i + 1);    // issue early (T14)
        COMPUTE(a0r, kp0 + i);
        if (i + 2 < ntap) LOADA(a0r, kp0 + i + 2);
        if (i + 1 < ntap) COMPUTE(a1r, kp0 + i + 1);
    }

    // ---- merge quad1 partials into quad0 via LDS (xs dead now)
    __syncthreads();
    float* msm = (float*)pool;            // 64KB: plane (n*16+r) x 256 f32
    #pragma unroll
    for (int m = 0; m < 2; ++m) {
        if (quad == 1) {
            #pragma unroll
            for (int n = 0; n < 4; ++n)
                #pragma unroll
                for (int r = 0; r < 16; ++r)
                    msm[(n * 16 + r) * 256 + ww * 64 + lane] = acc[m][n][r];
        }
        __syncthreads();
        if (quad == 0) {
            #pragma unroll
            for (int n = 0; n < 4; ++n)
                #pragma unroll
                for (int r = 0; r < 16; ++r)
                    acc[m][n][r] += msm[(n * 16 + r) * 256 + ww * 64 + lane];
        }
        __syncthreads();
    }

    // ---- epilogue (quad0): D col = l31 -> t, row = (r&3)+8*(r>>2)+4*kg -> o
    if (quad == 0) {
        const int ybase = (bb * COUT) * T_LEN;
        #pragma unroll
        for (int m = 0; m < 2; ++m) {
            #pragma unroll
            for (int n = 0; n < 4; ++n) {
                const int t = t0 + twbase + n * 32 + l31;
                #pragma unroll
                for (int r = 0; r < 16; ++r) {
                    const int o = m * 32 + (r & 3) + 8 * (r >> 2) + 4 * kg;
                    y[ybase + o * T_LEN + t] = acc[m][n][r];
                }
            }
        }
    }
}

extern "C" void kernel_launch(void* const* d_in, const int* in_sizes, int n_in,
                              void* d_out, int out_size, void* d_ws, size_t ws_size,
                              hipStream_t stream) {
    const float* x = (const float*)d_in[0];
    const float* W = (const float*)d_in[1];
    float* yout = (float*)d_out;
    unsigned short* Wt = (unsigned short*)d_ws;   // 127*4096*2 B ~= 1 MB

    wt_transform<<<16, 256, 0, stream>>>(W, Wt);

    const int grid = 8 * (T_LEN / TN);            // 256 blocks
    conv_mfma<<<grid, 512, 0, stream>>>(x, Wt, yout);
}

// Round 7
// 119.730 us; speedup vs baseline: 1.2466x; 1.0514x over previous
//
#include <hip/hip_runtime.h>

#define T_LEN 16384
#define CIN   64
#define COUT  64
#define KTAPS 127
#define TN    512          // t-tile per block
#define XROWS 640          // staged x rows
#define WT_KS 4096         // COUT*CIN halfwords per tap slice

typedef __attribute__((ext_vector_type(8)))  __bf16 bf16x8;
typedef __attribute__((ext_vector_type(16))) float  f32x16;
typedef __attribute__((ext_vector_type(4)))  float  float4v;

__device__ inline unsigned short f2bf(float f) {
    unsigned u = __builtin_bit_cast(unsigned, f);
    u += 0x7fffu + ((u >> 16) & 1u);        // round-to-nearest-even
    return (unsigned short)(u >> 16);
}

// Wt[kp] slice (8KB) in MFMA-fragment order: each lane's A-fragment is one
// contiguous 16B chunk. Chunk c (0..511) of slice kp holds, for
// f=c>>6 (=cc*2+m), kg=(c>>5)&1, l31=c&31:
//   e=0..7:  bf16(W[m*32+l31][cc*16+kg*8+e][126-kp])
// One thread per 16B chunk -> fully coalesced stores.
__global__ void wt_transform(const float* __restrict__ W,
                             unsigned short* __restrict__ Wt) {
    int t  = blockIdx.x * 256 + threadIdx.x;    // 127*512 threads
    int kp = t >> 9, c = t & 511;
    int f = c >> 6, kg = (c >> 5) & 1, l31 = c & 31;
    int cc = f >> 1, m = f & 1;
    int o = m * 32 + l31, ib = cc * 16 + kg * 8;
    const float* src = W + (o * CIN + ib) * KTAPS + (126 - kp);
    unsigned short tmp[8];
    #pragma unroll
    for (int e = 0; e < 8; ++e)
        tmp[e] = f2bf(src[e * KTAPS]);
    uint4 pk;
    pk.x = (unsigned)tmp[0] | ((unsigned)tmp[1] << 16);
    pk.y = (unsigned)tmp[2] | ((unsigned)tmp[3] << 16);
    pk.z = (unsigned)tmp[4] | ((unsigned)tmp[5] << 16);
    pk.w = (unsigned)tmp[6] | ((unsigned)tmp[7] << 16);
    *(uint4*)(Wt + kp * WT_KS + c * 8) = pk;
}

__global__ __launch_bounds__(512, 2)
void conv_mfma(const float* __restrict__ x,
               const unsigned short* __restrict__ Wt,
               float* __restrict__ y) {
    // pool: xs [0,80K)  (merge scratch reuses [0,64K) at the end)
    __shared__ __align__(16) char pool[81920];
    unsigned short* xs = (unsigned short*)pool;   // [XROWS][64] swizzled

    const int tid = threadIdx.x;
    const int bb  = blockIdx.x >> 5;      // batch
    const int tt  = blockIdx.x & 31;      // t-tile
    const int t0  = tt * TN;

    // ---- stage x window [t0-64, t0+575] transposed, 16-slot 8B swizzle:
    //      row w, cin c stored at w*64 + ((c>>2 ^ (w&15))<<2) + (c&3)
    {
        const int cin = tid >> 3;             // 0..63
        const int s   = tid & 7;
        const float* xrow = x + (bb * CIN + cin) * T_LEN;
        const int p = cin >> 2, c3 = cin & 3;
        for (int j = 0; j < 20; ++j) {
            const int w = 32 * j + 4 * s;
            const int u = t0 - 64 + w;        // global t (16B aligned)
            float4v v;
            if (u >= 0 && u + 4 <= T_LEN) {
                v = *(const float4v*)(xrow + u);
            } else {
                v.x = (u + 0 >= 0 && u + 0 < T_LEN) ? xrow[u + 0] : 0.f;
                v.y = (u + 1 >= 0 && u + 1 < T_LEN) ? xrow[u + 1] : 0.f;
                v.z = (u + 2 >= 0 && u + 2 < T_LEN) ? xrow[u + 2] : 0.f;
                v.w = (u + 3 >= 0 && u + 3 < T_LEN) ? xrow[u + 3] : 0.f;
            }
            #pragma unroll
            for (int e = 0; e < 4; ++e) {
                const int we = w + e;
                const float fv = (e == 0) ? v.x : (e == 1) ? v.y : (e == 2) ? v.z : v.w;
                xs[we * 64 + ((p ^ (we & 15)) << 2) + c3] = f2bf(fv);
            }
        }
    }

    const int lane   = tid & 63;
    const int wv     = tid >> 6;          // 0..7
    const int quad   = wv >> 2;           // tap-half owner
    const int ww     = wv & 3;            // wave-in-quad: t-range
    const int l31    = lane & 31;
    const int kg     = lane >> 5;
    const int twbase = ww * 128;          // wave's 128-t range
    const int brow0  = twbase + l31 + 1;  // xs row at k'=0

    const int kp0  = quad ? 64 : 0;
    const int ntap = quad ? 63 : 64;

    // per-lane A-fragment global base: + kp*8192 + f*1024, f = cc*2+m
    const char* ab = (const char*)Wt + lane * 16;

    f32x16 acc[2][4] = {};                // [m: o-tile][n: t-tile]
    uint4 a0r[8], a1r[8];                 // ping-pong A prefetch (cross-tap)
    uint2 bAlo[4], bAhi[4];               // B reg double-buffer (cross-cc)
    uint2 bBlo[4], bBhi[4];

    #define LOADA(dst, kp)                                                  \
        do { const char* p_ = ab + (kp) * 8192;                             \
            _Pragma("unroll")                                               \
            for (int f = 0; f < 8; ++f)                                     \
                dst[f] = *(const uint4*)(p_ + f * 1024); } while (0)

    // issue 8 ds_read_b64 for (row rb, cin-chunk cidx) into lo/hi
    #define LOADB(lo, hi, rb, cidx)                                         \
        do { const int rb15_ = (rb) & 15;                                   \
            const char* xp_ = (const char*)xs + (rb) * 128;                 \
            const int q0_ = (((4 * (cidx) + 2 * kg + 0) ^ rb15_) << 3);     \
            const int q1_ = (((4 * (cidx) + 2 * kg + 1) ^ rb15_) << 3);     \
            _Pragma("unroll")                                               \
            for (int n = 0; n < 4; ++n) {                                   \
                lo[n] = *(const uint2*)(xp_ + n * 4096 + q0_);              \
                hi[n] = *(const uint2*)(xp_ + n * 4096 + q1_);              \
            } } while (0)

    #define MFMAB(lo, hi, ar, cidx)                                         \
        do { bf16x8 a0 = __builtin_bit_cast(bf16x8, ar[(cidx) * 2 + 0]);    \
            bf16x8 a1 = __builtin_bit_cast(bf16x8, ar[(cidx) * 2 + 1]);     \
            _Pragma("unroll")                                               \
            for (int n = 0; n < 4; ++n) {                                   \
                uint4 t4 = {lo[n].x, lo[n].y, hi[n].x, hi[n].y};            \
                bf16x8 b = __builtin_bit_cast(bf16x8, t4);                  \
                acc[0][n] = __builtin_amdgcn_mfma_f32_32x32x16_bf16(a0, b, acc[0][n], 0, 0, 0); \
                acc[1][n] = __builtin_amdgcn_mfma_f32_32x32x16_bf16(a1, b, acc[1][n], 0, 0, 0); \
            } } while (0)

    // one tap, B-pipelined: prefetch next cc's B before current cc's MFMAs.
    // Invariant: bA holds B(kp, cc=0) on entry; holds B(kp+1, cc=0) on exit.
    // do-while(0) so an `if (...) TAP(...)` guards the WHOLE tap (R6 bug).
    #define TAP(ar, kp)                                                     \
        do {                                                                \
            LOADB(bBlo, bBhi, brow0 + (kp), 1);  MFMAB(bAlo, bAhi, ar, 0);  \
            LOADB(bAlo, bAhi, brow0 + (kp), 2);  MFMAB(bBlo, bBhi, ar, 1);  \
            LOADB(bBlo, bBhi, brow0 + (kp), 3);  MFMAB(bAlo, bAhi, ar, 2);  \
            LOADB(bAlo, bAhi, brow0 + (kp) + 1, 0); MFMAB(bBlo, bBhi, ar, 3); \
        } while (0)

    LOADA(a0r, kp0);                       // overlaps the barrier
    __syncthreads();                       // xs ready (only barrier pre-merge)
    LOADB(bAlo, bAhi, brow0 + kp0, 0);     // prime B pipeline

    // barrier-free main loop: waves drift freely over their tap ranges
    for (int i = 0; i < ntap; i += 2) {
        if (i + 1 < ntap) LOADA(a1r, kp0 + i + 1);    // A issue-early
        TAP(a0r, kp0 + i);
        if (i + 2 < ntap) LOADA(a0r, kp0 + i + 2);
        if (i + 1 < ntap) TAP(a1r, kp0 + i + 1);
    }

    // ---- merge quad1 partials into quad0 via LDS (xs dead now)
    __syncthreads();
    float* msm = (float*)pool;            // 64KB: plane (n*16+r) x 256 f32
    #pragma unroll
    for (int m = 0; m < 2; ++m) {
        if (quad == 1) {
            #pragma unroll
            for (int n = 0; n < 4; ++n)
                #pragma unroll
                for (int r = 0; r < 16; ++r)
                    msm[(n * 16 + r) * 256 + ww * 64 + lane] = acc[m][n][r];
        }
        __syncthreads();
        if (quad == 0) {
            #pragma unroll
            for (int n = 0; n < 4; ++n)
                #pragma unroll
                for (int r = 0; r < 16; ++r)
                    acc[m][n][r] += msm[(n * 16 + r) * 256 + ww * 64 + lane];
        }
        __syncthreads();
    }

    // ---- epilogue (quad0): D col = l31 -> t, row = (r&3)+8*(r>>2)+4*kg -> o
    if (quad == 0) {
        const int ybase = (bb * COUT) * T_LEN;
        #pragma unroll
        for (int m = 0; m < 2; ++m) {
            #pragma unroll
            for (int n = 0; n < 4; ++n) {
                const int t = t0 + twbase + n * 32 + l31;
                #pragma unroll
                for (int r = 0; r < 16; ++r) {
                    const int o = m * 32 + (r & 3) + 8 * (r >> 2) + 4 * kg;
                    y[ybase + o * T_LEN + t] = acc[m][n][r];
                }
            }
        }
    }
}

extern "C" void kernel_launch(void* const* d_in, const int* in_sizes, int n_in,
                              void* d_out, int out_size, void* d_ws, size_t ws_size,
                              hipStream_t stream) {
    const float* x = (const float*)d_in[0];
    const float* W = (const float*)d_in[1];
    float* yout = (float*)d_out;
    unsigned short* Wt = (unsigned short*)d_ws;   // 127*4096*2 B ~= 1 MB

    wt_transform<<<(KTAPS * 512) / 256, 256, 0, stream>>>(W, Wt);

    const int grid = 8 * (T_LEN / TN);            // 256 blocks
    conv_mfma<<<grid, 512, 0, stream>>>(x, Wt, yout);
}